// Round 9
// baseline (788.797 us; speedup 1.0000x reference)
//
#include <hip/hip_runtime.h>
#include <hip/hip_cooperative_groups.h>
namespace cg = cooperative_groups;

// Problem constants: B=16,N=100,E=9900,M=50,F=64,H=128,K=20,D=2,T=8,S=8
#define BB 16
#define NN 100
#define EE 9900
#define MM 50
#define FF 64
#define KK 20
#define DD 2
#define ROWS (BB*EE)      // 158400 edge rows
#define HROWS (BB*MM)     // 800 hyper rows
#define BN_CNT (BB*NN)    // 1600
#define NTILE (ROWS/64)   // 2475 tiles of 64 rows
#define GRIDC 256         // cooperative grid: <=1 block/CU guaranteed co-resident
#define GEMMB 512         // fallback gemm grid
#define EPSF 1e-5f
#define XPITCH 136

typedef __attribute__((ext_vector_type(8))) short bf16x8;
typedef __attribute__((ext_vector_type(4))) float f32x4;

__device__ __forceinline__ float lrelu(float x) { return (x >= 0.f) ? x : 0.01f * x; }

__device__ __forceinline__ unsigned short f2bf(float x) {
  unsigned u = __float_as_uint(x);
  return (unsigned short)((u + 0x7fffu + ((u >> 16) & 1u)) >> 16);
}
__device__ __forceinline__ unsigned pk2(float a, float b) {
  return (unsigned)f2bf(a) | ((unsigned)f2bf(b) << 16);
}
__device__ __forceinline__ float bf2f(unsigned short u) {
  return __uint_as_float(((unsigned)u) << 16);
}

// ---------------- Threefry-2x32 (bit-exact vs JAX, partitionable XOR mode) -----------
__device__ __forceinline__ void tf2x32(unsigned k0, unsigned k1,
                                       unsigned x0, unsigned x1,
                                       unsigned& o0, unsigned& o1) {
  unsigned ks2 = k0 ^ k1 ^ 0x1BD11BDAu;
  x0 += k0; x1 += k1;
#define TFR(r) { x0 += x1; x1 = (x1 << r) | (x1 >> (32 - r)); x1 ^= x0; }
  TFR(13) TFR(15) TFR(26) TFR(6)   x0 += k1;  x1 += ks2 + 1u;
  TFR(17) TFR(29) TFR(16) TFR(24)  x0 += ks2; x1 += k0 + 2u;
  TFR(13) TFR(15) TFR(26) TFR(6)   x0 += k0;  x1 += k1 + 3u;
  TFR(17) TFR(29) TFR(16) TFR(24)  x0 += k1;  x1 += ks2 + 4u;
  TFR(13) TFR(15) TFR(26) TFR(6)   x0 += ks2; x1 += k0 + 5u;
#undef TFR
  o0 = x0; o1 = x1;
}

__device__ __forceinline__ float bits_to_normal(unsigned bits) {
  float f = __uint_as_float((bits >> 9) | 0x3f800000u) - 1.0f;  // [0,1)
  const float lo = -0.99999994f;                                 // nextafter(-1,0)
  float x = fmaxf(lo, fmaf(f, 2.0f, lo));
  float w = -log1pf(-x * x);
  float p;
  if (w < 5.0f) {
    w = w - 2.5f;
    p = 2.81022636e-08f;
    p = fmaf(p, w, 3.43273939e-07f);
    p = fmaf(p, w, -3.5233877e-06f);
    p = fmaf(p, w, -4.39150654e-06f);
    p = fmaf(p, w, 0.00021858087f);
    p = fmaf(p, w, -0.00125372503f);
    p = fmaf(p, w, -0.00417768164f);
    p = fmaf(p, w, 0.246640727f);
    p = fmaf(p, w, 1.50140941f);
  } else {
    w = sqrtf(w) - 3.0f;
    p = -0.000200214257f;
    p = fmaf(p, w, 0.000100950558f);
    p = fmaf(p, w, 0.00134934322f);
    p = fmaf(p, w, -0.00367342844f);
    p = fmaf(p, w, 0.00573950773f);
    p = fmaf(p, w, -0.0076224613f);
    p = fmaf(p, w, 0.00943887047f);
    p = fmaf(p, w, 1.00167406f);
    p = fmaf(p, w, 2.83297682f);
  }
  return 1.41421356237f * (p * x);
}

// ---------------- shared-memory types ----------------
struct SmemGemm {
  unsigned short Xt[64 * XPITCH];
  float aColP[132], bColP[132];
  float bsum[128], bssq[128];
};
struct SmemVe {
  float cat[2][256], vres[2][128], lgs[2][KK], mrow[2][KK * DD], alsh[2][KK];
};
struct SmemH {
  float prerow[2][FF];
  float trow[2][128];
};
struct SmemOut {
  float nz[4][8][2], ins[4][8][2], alsh[4][KK];
};
union Smem {
  SmemGemm g;
  SmemVe ve;
  SmemH h;
  SmemOut o;
};

struct Params {
  const float *data, *rtg, *rth, *I_HG, *v;
  const float *W1g, *b1g, *g1g, *be1g, *W2g, *b2g, *g2g, *be2g;
  const float *W1h, *b1h, *g1h, *be1h, *W2h, *b2h, *g2h, *be2h;
  const float *Wo1, *bo1, *Wa, *ba, *Wm, *bm;
  unsigned short *Ybf, *WtG;
  float *stats1, *stats2, *statsh1, *statsh2, *scaleg, *scaleh;
  float *hg, *hh, *y1h, *y2h, *va, *vmu, *vcore, *partials, *partial2;
  float *out;
};

// ================= phase functions (shared by fused + fallback kernels) ==============

__device__ __forceinline__ void prep_phase(const Params& p, int bid, int nblk, int tid) {
  for (int i = bid * 256 + tid; i < ROWS + HROWS; i += nblk * 256) {
    if (i < ROWS) {
      float4 r = ((const float4*)p.rtg)[i];
      p.scaleg[i] = (r.x + r.y + r.z + r.w) * 0.25f;
    } else {
      float4 r = ((const float4*)p.rth)[i - ROWS];
      p.scaleh[i - ROWS] = (r.x + r.y + r.z + r.w) * 0.25f;
    }
  }
  for (int i = bid * 256 + tid; i < 32768; i += nblk * 256) {
    int w = i >> 14, rem = i & 16383;
    int c = rem & 127, k = rem >> 7;
    const float* W = w ? p.W2g : p.W1g;
    p.WtG[w * 16384 + c * 128 + k] = f2bf(W[k * 128 + c]);
  }
}

// grid-strided 5..10-tile pipelined bf16 MFMA GEMM; per-block partial stats.
template <int MODE>
__device__ __forceinline__ void edge_gemm_phase(
    const Params& p, SmemGemm& sg, int bid, int nblk, int tid,
    const unsigned short* WtG, const unsigned short* Yin, unsigned short* Yout,
    const float* bias, const float* gmm, const float* beta,
    const float* stats_in) {
  const int lane = tid & 63, wid = tid >> 6;
  const int l15 = lane & 15, lq = lane >> 4;
  const int cb = wid * 32;
  const int rsi = tid >> 2, q = tid & 3, k0 = q * 32;

  if (tid < 128) {
    sg.bsum[tid] = 0.f; sg.bssq[tid] = 0.f;
    if (MODE == 1) {
      float s = stats_in[tid], ss = stats_in[128 + tid];
      float mu = s * (1.f / ROWS);
      float var = fmaxf(ss * (1.f / ROWS) - mu * mu, 0.f);
      float rs = 1.f / sqrtf(var + EPSF);
      float a = rs * gmm[tid];
      int pi = tid + (tid >> 5);
      sg.aColP[pi] = a; sg.bColP[pi] = beta[tid] - mu * a;
    }
  }

  const unsigned short* WA = WtG + (cb + l15) * 128 + lq * 8;
  bf16x8 a0[4], a1[4];
#pragma unroll
  for (int kc = 0; kc < 4; ++kc) {
    a0[kc] = *(const bf16x8*)(WA + kc * 32);
    a1[kc] = *(const bf16x8*)(WA + 16 * 128 + kc * 32);
  }
  float4 bi0 = *(const float4*)&bias[cb + lq * 4];
  float4 bi1 = *(const float4*)&bias[cb + 16 + lq * 4];
  f32x4 bv0 = {bi0.x, bi0.y, bi0.z, bi0.w};
  f32x4 bv1 = {bi1.x, bi1.y, bi1.z, bi1.w};
  f32x4 s0 = {0.f,0.f,0.f,0.f}, ss0 = {0.f,0.f,0.f,0.f};
  f32x4 s1 = {0.f,0.f,0.f,0.f}, ss1 = {0.f,0.f,0.f,0.f};

  float4 ra[4], rb[4];
  uint4  rw[4];

  auto LOAD = [&](int tile) {
    if (MODE == 0) {
      int g = tile * 64 + rsi;
      int b = g / EE; int e = g - b * EE;
      int i = e / 99; int jj = e - i * 99; int j = jj + ((jj >= i) ? 1 : 0);
      int vsrc = (q < 2) ? ((b * NN + i) * FF + q * 32)
                         : ((b * NN + j) * FF + (q - 2) * 32);
#pragma unroll
      for (int i2 = 0; i2 < 4; ++i2) {
        ra[i2] = *(const float4*)&p.v[vsrc + i2 * 8];
        rb[i2] = *(const float4*)&p.v[vsrc + i2 * 8 + 4];
      }
    } else {
      const unsigned short* src = Yin + (size_t)(tile * 64 + rsi) * 128 + k0;
#pragma unroll
      for (int i2 = 0; i2 < 4; ++i2) rw[i2] = *(const uint4*)&src[i2 * 8];
    }
  };
  auto WRITE = [&]() {
    if (MODE == 0) {
#pragma unroll
      for (int i2 = 0; i2 < 4; ++i2) {
        uint4 pk;
        pk.x = pk2(ra[i2].x, ra[i2].y); pk.y = pk2(ra[i2].z, ra[i2].w);
        pk.z = pk2(rb[i2].x, rb[i2].y); pk.w = pk2(rb[i2].z, rb[i2].w);
        *(uint4*)&sg.Xt[rsi * XPITCH + k0 + i2 * 8] = pk;
      }
    } else {
#pragma unroll
      for (int i2 = 0; i2 < 4; ++i2) {
        unsigned rr[4] = {rw[i2].x, rw[i2].y, rw[i2].z, rw[i2].w};
        unsigned ow[4];
#pragma unroll
        for (int u = 0; u < 4; ++u) {
          int k = k0 + i2 * 8 + u * 2;
          int p1 = k + (k >> 5);
          float xl = __uint_as_float(rr[u] << 16);
          float xh = __uint_as_float(rr[u] & 0xffff0000u);
          xl = lrelu(fmaf(xl, sg.aColP[p1], sg.bColP[p1]));
          xh = lrelu(fmaf(xh, sg.aColP[p1 + 1], sg.bColP[p1 + 1]));
          ow[u] = pk2(xl, xh);
        }
        uint4 pk; pk.x = ow[0]; pk.y = ow[1]; pk.z = ow[2]; pk.w = ow[3];
        *(uint4*)&sg.Xt[rsi * XPITCH + k0 + i2 * 8] = pk;
      }
    }
  };

  if (MODE == 1) __syncthreads();   // aColP/bColP visible before first WRITE

  LOAD(bid);
  for (int t = bid; t < NTILE; t += nblk) {
    if (t != bid) __syncthreads();  // prior tile's MFMA reads of Xt complete
    WRITE();
    if (t + nblk < NTILE) LOAD(t + nblk);   // prefetch overlaps MFMA+epilogue
    __syncthreads();                // Xt ready

    f32x4 acc[2][4];
#pragma unroll
    for (int a = 0; a < 2; ++a)
#pragma unroll
      for (int b2 = 0; b2 < 4; ++b2) acc[a][b2] = (f32x4){0.f, 0.f, 0.f, 0.f};
    const unsigned short* Bb = &sg.Xt[l15 * XPITCH + lq * 8];
#pragma unroll
    for (int kc = 0; kc < 4; ++kc) {
      int ko = kc * 32;
#pragma unroll
      for (int rbi = 0; rbi < 4; ++rbi) {
        bf16x8 bfr = *(const bf16x8*)(Bb + rbi * 16 * XPITCH + ko);
        acc[0][rbi] = __builtin_amdgcn_mfma_f32_16x16x32_bf16(a0[kc], bfr, acc[0][rbi], 0, 0, 0);
        acc[1][rbi] = __builtin_amdgcn_mfma_f32_16x16x32_bf16(a1[kc], bfr, acc[1][rbi], 0, 0, 0);
      }
    }

    int r0 = t * 64;
#pragma unroll
    for (int rbi = 0; rbi < 4; ++rbi) {
      size_t r = (size_t)(r0 + rbi * 16 + l15);
      f32x4 y0 = acc[0][rbi] + bv0;
      f32x4 y1 = acc[1][rbi] + bv1;
      uint2 w0; w0.x = pk2(y0.x, y0.y); w0.y = pk2(y0.z, y0.w);
      uint2 w1; w1.x = pk2(y1.x, y1.y); w1.y = pk2(y1.z, y1.w);
      *(uint2*)&Yout[r * 128 + cb + lq * 4] = w0;
      *(uint2*)&Yout[r * 128 + cb + 16 + lq * 4] = w1;
      s0 += y0; ss0 += y0 * y0;
      s1 += y1; ss1 += y1 * y1;
    }
  }

#pragma unroll
  for (int u = 0; u < 4; ++u) {
    atomicAdd(&sg.bsum[cb + lq * 4 + u], s0[u]);
    atomicAdd(&sg.bssq[cb + lq * 4 + u], ss0[u]);
    atomicAdd(&sg.bsum[cb + 16 + lq * 4 + u], s1[u]);
    atomicAdd(&sg.bssq[cb + 16 + lq * 4 + u], ss1[u]);
  }
  __syncthreads();
  if (tid < 128) {
    p.partials[(size_t)bid * 256 + tid] = sg.bsum[tid];
    p.partials[(size_t)bid * 256 + 128 + tid] = sg.bssq[tid];
  }
}

__device__ __forceinline__ void redA_phase(const float* partials, float* partial2,
                                           int nblk, int bid, int tid) {
  if (bid < 32) {
    float s = 0.f;
    for (int r = bid; r < nblk; r += 32) s += partials[(size_t)r * 256 + tid];
    partial2[bid * 256 + tid] = s;
  }
}
__device__ __forceinline__ void redB_phase(const float* partial2, float* stats,
                                           int bid, int tid) {
  if (bid == 0) {
    float s = 0.f;
#pragma unroll
    for (int r = 0; r < 32; ++r) s += partial2[r * 256 + tid];
    stats[tid] = s;
  }
}

__device__ __forceinline__ void recv_phase(const Params& p, int bid, int nblk, int tid) {
  const int sub = tid >> 7, h = tid & 127;
  float s = p.stats2[h], ss = p.stats2[128 + h];
  float mu = s * (1.f / ROWS);
  float var = fmaxf(ss * (1.f / ROWS) - mu * mu, 0.f);
  float rs = 1.f / sqrtf(var + EPSF);
  float a = rs * p.g2g[h]; float bc = p.be2g[h] - mu * a;
  for (int bn = bid * 2 + sub; bn < BN_CNT; bn += 2 * nblk) {
    int b = bn / NN, n = bn - b * NN;
    float sv = (h >= 64) ? p.v[(b * NN + n) * FF + (h - 64)] : 0.f;
    float acc = 0.f;
#pragma unroll 4
    for (int i = 0; i < NN; ++i) {
      if (i == n) continue;
      int e = i * 99 + ((n < i) ? n : n - 1);
      int row = b * EE + e;
      float y = bf2f(p.Ybf[(size_t)row * 128 + h]);
      float msgv = lrelu(y * a + bc);
      float pre = (h < 64) ? p.v[(b * NN + i) * FF + h] : sv;
      float ag = lrelu(fmaf(msgv, p.scaleg[row], pre));
      acc += ag;
    }
    p.hg[bn * 128 + h] = acc * 0.5f;
  }
}

// HROWS and BN_CNT are even and strides are even -> per-block uniform trip counts,
// so the __syncthreads() inside these loops are safe.
__device__ __forceinline__ void h1_phase(const Params& p, SmemH& sh, int bid, int nblk, int tid) {
  const int sub = tid >> 7, ht = tid & 127;
  for (int bm = bid * 2 + sub; bm < HROWS; bm += 2 * nblk) {
    int b = bm / MM, m = bm - b * MM;
    if (ht < FF) {
      float s = 0.f;
      for (int n = 0; n < NN; ++n)
        s = fmaf(p.I_HG[(b * NN + n) * MM + m], p.v[(b * NN + n) * FF + ht], s);
      sh.prerow[sub][ht] = s;
    }
    __syncthreads();
    float y = p.b1h[ht];
    for (int f = 0; f < FF; ++f) y = fmaf(sh.prerow[sub][f], p.W1h[f * 128 + ht], y);
    p.y1h[bm * 128 + ht] = y;
    __syncthreads();
  }
}

__device__ __forceinline__ void cs_phase(const float* X, float* stats, int bid, int tid) {
  if (bid < 32) {
    int c = bid * 4 + (tid >> 6), rt = tid & 63;
    float s = 0.f, ss = 0.f;
    for (int r = rt; r < HROWS; r += 64) {
      float x = X[(size_t)r * 128 + c];
      s += x; ss += x * x;
    }
    for (int off = 32; off; off >>= 1) {
      s += __shfl_down(s, off, 64);
      ss += __shfl_down(ss, off, 64);
    }
    if (rt == 0) { stats[c] = s; stats[128 + c] = ss; }
  }
}

__device__ __forceinline__ void h2_phase(const Params& p, SmemH& sh, int bid, int nblk, int tid) {
  const int sub = tid >> 7, ht = tid & 127;
  float s = p.statsh1[ht], ss = p.statsh1[128 + ht];
  float mu = s * (1.f / HROWS);
  float var = fmaxf(ss * (1.f / HROWS) - mu * mu, 0.f);
  float rs = 1.f / sqrtf(var + EPSF);
  float a = rs * p.g1h[ht]; float bc = p.be1h[ht] - mu * a;
  for (int bm = bid * 2 + sub; bm < HROWS; bm += 2 * nblk) {
    sh.trow[sub][ht] = lrelu(p.y1h[bm * 128 + ht] * a + bc);
    __syncthreads();
    float y = p.b2h[ht];
    for (int f = 0; f < 128; ++f) y = fmaf(sh.trow[sub][f], p.W2h[f * 128 + ht], y);
    p.y2h[bm * 128 + ht] = y;
    __syncthreads();
  }
}

__device__ __forceinline__ void h3_phase(const Params& p, int bid, int nblk, int tid) {
  const int sub = tid >> 7, h = tid & 127;
  float s = p.statsh2[h], ss = p.statsh2[128 + h];
  float mu = s * (1.f / HROWS);
  float var = fmaxf(ss * (1.f / HROWS) - mu * mu, 0.f);
  float rs = 1.f / sqrtf(var + EPSF);
  float a = rs * p.g2h[h]; float bc = p.be2h[h] - mu * a;
  for (int bn = bid * 2 + sub; bn < BN_CNT; bn += 2 * nblk) {
    int b = bn / NN, n = bn - b * NN;
    float acc = 0.f;
    for (int m = 0; m < MM; ++m) {
      float x = lrelu(p.y2h[(b * MM + m) * 128 + h] * a + bc);
      acc = fmaf(x * p.scaleh[b * MM + m], p.I_HG[(b * NN + n) * MM + m], acc);
    }
    p.hh[bn * 128 + h] = acc * 0.5f;
  }
}

__device__ __forceinline__ void ve_phase(const Params& p, SmemVe& sv, int bid, int nblk, int tid) {
  const int sub = tid >> 7, ht = tid & 127;
  for (int bn = bid * 2 + sub; bn < BN_CNT; bn += 2 * nblk) {
    sv.cat[sub][ht] = p.hg[bn * 128 + ht];
    sv.cat[sub][128 + ht] = p.hh[bn * 128 + ht];
    __syncthreads();
    float vv = p.bo1[ht];
    for (int k = 0; k < 256; ++k)
      vv = fmaf(sv.cat[sub][k], p.Wo1[k * 128 + ht], vv);
    sv.vres[sub][ht] = lrelu(vv);
    __syncthreads();
    if (ht < KK) {
      float s = p.ba[ht];
      for (int f = 0; f < 128; ++f) s = fmaf(sv.vres[sub][f], p.Wa[f * KK + ht], s);
      sv.lgs[sub][ht] = s;
    } else if (ht >= 64 && ht < 64 + KK * DD) {
      int c = ht - 64;
      float s = p.bm[c];
      for (int f = 0; f < 128; ++f) s = fmaf(sv.vres[sub][f], p.Wm[f * (KK * DD) + c], s);
      sv.mrow[sub][c] = s;
      p.vmu[bn * (KK * DD) + c] = s;
    }
    __syncthreads();
    if (ht < KK) {
      float mx = sv.lgs[sub][0];
      for (int k2 = 1; k2 < KK; ++k2) mx = fmaxf(mx, sv.lgs[sub][k2]);
      float se = 0.f;
      for (int k2 = 0; k2 < KK; ++k2) se += expf(sv.lgs[sub][k2] - mx);
      float al = expf(sv.lgs[sub][ht] - mx) / se;
      sv.alsh[sub][ht] = al;
      p.va[bn * KK + ht] = al;
    }
    __syncthreads();
    if (ht < DD) {
      float s = 0.f;
      for (int k2 = 0; k2 < KK; ++k2)
        s = fmaf(sv.alsh[sub][k2], sv.mrow[sub][k2 * DD + ht], s);
      p.vcore[bn * DD + ht] = s;
    }
    __syncthreads();
  }
}

__device__ __forceinline__ void out_phase(const Params& p, SmemOut& so, int bid, int nblk, int tid) {
  const int ut = tid >> 6, t = tid & 63;
  for (int bn = bid * 4 + ut; bn < BN_CNT; bn += 4 * nblk) {
    if (t < 16) {
      int s = t >> 1, d = t & 1;
      unsigned fk0, fk1;
      tf2x32(0u, 1234u, 0u, (unsigned)s, fk0, fk1);
      unsigned flat = (unsigned)(bn * 2 + d);
      unsigned o0, o1;
      tf2x32(fk0, fk1, 0u, flat, o0, o1);
      so.nz[ut][s][d] = bits_to_normal(o0 ^ o1);
    }
    if (t < KK) so.alsh[ut][t] = p.va[bn * KK + t];
    __syncthreads();
    if (t < 2) {
      int d = t;
      float ins0 = p.data[bn * 16 + d];
      float core = p.vcore[bn * 2 + d];
      float pp = ins0;
      for (int s = 0; s < 8; ++s) {
        so.ins[ut][s][d] = pp;
        pp = (pp + core) + so.nz[ut][s][d];
        p.out[(bn * 8 + s) * 2 + d] = pp;
      }
    }
    __syncthreads();
    for (int q = t; q < 160; q += 64) {
      int k = q % KK;
      p.out[25600 + bn * 160 + q] = so.alsh[ut][k];
    }
    for (int q = t; q < 320; q += 64) {
      int s = q / 40, kd = q - s * 40, d = kd & 1;
      p.out[281600 + bn * 320 + q] = p.vmu[bn * 40 + kd] + so.ins[ut][s][d];
    }
    for (int q = t; q < 320; q += 64) p.out[793600 + bn * 320 + q] = 1.0f;
    __syncthreads();
  }
}

// ================= fused cooperative kernel (256 blocks) =================
__global__ __launch_bounds__(256, 2) void k_fused(Params p) {
  cg::grid_group gg = cg::this_grid();
  __shared__ __align__(16) Smem sm;
  const int bid = blockIdx.x, tid = threadIdx.x;

  prep_phase(p, bid, GRIDC, tid);
  gg.sync();
  edge_gemm_phase<0>(p, sm.g, bid, GRIDC, tid, p.WtG, nullptr, p.Ybf, p.b1g,
                     nullptr, nullptr, nullptr);
  gg.sync();
  redA_phase(p.partials, p.partial2, GRIDC, bid, tid);
  gg.sync();
  redB_phase(p.partial2, p.stats1, bid, tid);
  gg.sync();
  edge_gemm_phase<1>(p, sm.g, bid, GRIDC, tid, p.WtG + 16384, p.Ybf, p.Ybf, p.b2g,
                     p.g1g, p.be1g, p.stats1);
  gg.sync();
  redA_phase(p.partials, p.partial2, GRIDC, bid, tid);
  gg.sync();
  redB_phase(p.partial2, p.stats2, bid, tid);
  gg.sync();
  recv_phase(p, bid, GRIDC, tid);      // writes hg
  h1_phase(p, sm.h, bid, GRIDC, tid);  // writes y1h (disjoint from recv)
  gg.sync();
  cs_phase(p.y1h, p.statsh1, bid, tid);
  gg.sync();
  h2_phase(p, sm.h, bid, GRIDC, tid);
  gg.sync();
  cs_phase(p.y2h, p.statsh2, bid, tid);
  gg.sync();
  h3_phase(p, bid, GRIDC, tid);
  gg.sync();
  ve_phase(p, sm.ve, bid, GRIDC, tid);
  gg.sync();
  out_phase(p, sm.o, bid, GRIDC, tid);
}

// ================= fallback wrapper kernels =================
__global__ __launch_bounds__(256) void k_prepW(Params p) {
  prep_phase(p, blockIdx.x, gridDim.x, threadIdx.x);
}
__global__ __launch_bounds__(256, 2) void k_gemm0W(Params p) {
  __shared__ __align__(16) SmemGemm sg;
  edge_gemm_phase<0>(p, sg, blockIdx.x, gridDim.x, threadIdx.x, p.WtG, nullptr,
                     p.Ybf, p.b1g, nullptr, nullptr, nullptr);
}
__global__ __launch_bounds__(256, 2) void k_gemm1W(Params p) {
  __shared__ __align__(16) SmemGemm sg;
  edge_gemm_phase<1>(p, sg, blockIdx.x, gridDim.x, threadIdx.x, p.WtG + 16384,
                     p.Ybf, p.Ybf, p.b2g, p.g1g, p.be1g, p.stats1);
}
__global__ __launch_bounds__(256) void k_redAW(const float* partials, float* partial2, int nblk) {
  redA_phase(partials, partial2, nblk, blockIdx.x, threadIdx.x);
}
__global__ __launch_bounds__(256) void k_redBW(const float* partial2, float* stats) {
  redB_phase(partial2, stats, blockIdx.x, threadIdx.x);
}
__global__ __launch_bounds__(256) void k_recvW(Params p) {
  recv_phase(p, blockIdx.x, gridDim.x, threadIdx.x);
}
__global__ __launch_bounds__(256) void k_h1W(Params p) {
  __shared__ SmemH sh;
  h1_phase(p, sh, blockIdx.x, gridDim.x, threadIdx.x);
}
__global__ __launch_bounds__(256) void k_csW(const float* X, float* stats) {
  cs_phase(X, stats, blockIdx.x, threadIdx.x);
}
__global__ __launch_bounds__(256) void k_h2W(Params p) {
  __shared__ SmemH sh;
  h2_phase(p, sh, blockIdx.x, gridDim.x, threadIdx.x);
}
__global__ __launch_bounds__(256) void k_h3W(Params p) {
  h3_phase(p, blockIdx.x, gridDim.x, threadIdx.x);
}
__global__ __launch_bounds__(256) void k_veW(Params p) {
  __shared__ SmemVe sv;
  ve_phase(p, sv, blockIdx.x, gridDim.x, threadIdx.x);
}
__global__ __launch_bounds__(256) void k_outW(Params p) {
  __shared__ SmemOut so;
  out_phase(p, so, blockIdx.x, gridDim.x, threadIdx.x);
}

extern "C" void kernel_launch(void* const* d_in, const int* in_sizes, int n_in,
                              void* d_out, int out_size, void* d_ws, size_t ws_size,
                              hipStream_t stream) {
  char* wsb = (char*)d_ws;

  Params p;
  p.data = (const float*)d_in[0];
  p.rtg  = (const float*)d_in[3];
  p.rth  = (const float*)d_in[4];
  p.I_HG = (const float*)d_in[5];
  p.v    = (const float*)d_in[6];
  p.W1g  = (const float*)d_in[7];
  p.b1g  = (const float*)d_in[8];
  p.g1g  = (const float*)d_in[9];
  p.be1g = (const float*)d_in[10];
  p.W2g  = (const float*)d_in[11];
  p.b2g  = (const float*)d_in[12];
  p.g2g  = (const float*)d_in[13];
  p.be2g = (const float*)d_in[14];
  p.W1h  = (const float*)d_in[15];
  p.b1h  = (const float*)d_in[16];
  p.g1h  = (const float*)d_in[17];
  p.be1h = (const float*)d_in[18];
  p.W2h  = (const float*)d_in[19];
  p.b2h  = (const float*)d_in[20];
  p.g2h  = (const float*)d_in[21];
  p.be2h = (const float*)d_in[22];
  p.Wo1  = (const float*)d_in[23];
  p.bo1  = (const float*)d_in[24];
  p.Wa   = (const float*)d_in[25];
  p.ba   = (const float*)d_in[26];
  p.Wm   = (const float*)d_in[27];
  p.bm   = (const float*)d_in[28];

  p.Ybf     = (unsigned short*)wsb;                                  // 40,550,400 B
  p.stats1  = (float*)(wsb + 40550400);
  p.stats2  = p.stats1 + 256;
  p.statsh1 = p.stats2 + 256;
  p.statsh2 = p.statsh1 + 256;
  p.scaleg  = (float*)(wsb + 40550400 + 4096);
  p.scaleh  = p.scaleg + ROWS;
  p.hg      = p.scaleh + HROWS;
  p.hh      = p.hg + BN_CNT * 128;
  p.y1h     = p.hh + BN_CNT * 128;
  p.y2h     = p.y1h + HROWS * 128;
  p.va      = p.y2h + HROWS * 128;
  p.vmu     = p.va + BN_CNT * KK;
  p.vcore   = p.vmu + BN_CNT * KK * DD;
  p.WtG     = (unsigned short*)(p.vcore + BN_CNT * DD);              // 2*16384 bf16
  p.partials = (float*)(p.WtG + 2 * 16384);                          // 512*256 f32 max
  p.partial2 = p.partials + (size_t)GEMMB * 256;                     // 32*256 f32
  p.out     = (float*)d_out;

  void* args[] = {(void*)&p};
  hipError_t err = hipLaunchCooperativeKernel((const void*)k_fused, dim3(GRIDC),
                                              dim3(256), args, 0, stream);
  if (err != hipSuccess) {
    // deterministic fallback: same phases as separate kernels
    k_prepW<<<256, 256, 0, stream>>>(p);
    k_gemm0W<<<GEMMB, 256, 0, stream>>>(p);
    k_redAW<<<32, 256, 0, stream>>>(p.partials, p.partial2, GEMMB);
    k_redBW<<<1, 256, 0, stream>>>(p.partial2, p.stats1);
    k_gemm1W<<<GEMMB, 256, 0, stream>>>(p);
    k_redAW<<<32, 256, 0, stream>>>(p.partials, p.partial2, GEMMB);
    k_redBW<<<1, 256, 0, stream>>>(p.partial2, p.stats2);
    k_recvW<<<800, 256, 0, stream>>>(p);
    k_h1W<<<400, 256, 0, stream>>>(p);
    k_csW<<<32, 256, 0, stream>>>(p.y1h, p.statsh1);
    k_h2W<<<400, 256, 0, stream>>>(p);
    k_csW<<<32, 256, 0, stream>>>(p.y2h, p.statsh2);
    k_h3W<<<800, 256, 0, stream>>>(p);
    k_veW<<<800, 256, 0, stream>>>(p);
    k_outW<<<400, 256, 0, stream>>>(p);
  }
}

// Round 10
// 303.332 us; speedup vs baseline: 2.6004x; 2.6004x over previous
//
#include <hip/hip_runtime.h>

// Problem constants: B=16,N=100,E=9900,M=50,F=64,H=128,K=20,D=2,T=8,S=8
#define BB 16
#define NN 100
#define EE 9900
#define MM 50
#define FF 64
#define KK 20
#define DD 2
#define ROWS (BB*EE)      // 158400 edge rows
#define HROWS (BB*MM)     // 800 hyper rows
#define BN_CNT (BB*NN)    // 1600
#define NTILE (ROWS/64)   // 2475 tiles of 64 rows
#define GEMMB 512         // gemm grid (grid-stride, ~4.8 tiles/block pipelined)
#define EPSF 1e-5f
#define XPITCH 136

typedef __attribute__((ext_vector_type(8))) short bf16x8;
typedef __attribute__((ext_vector_type(4))) float f32x4;

__device__ __forceinline__ float lrelu(float x) { return (x >= 0.f) ? x : 0.01f * x; }

__device__ __forceinline__ unsigned short f2bf(float x) {
  unsigned u = __float_as_uint(x);
  return (unsigned short)((u + 0x7fffu + ((u >> 16) & 1u)) >> 16);
}
__device__ __forceinline__ unsigned pk2(float a, float b) {
  return (unsigned)f2bf(a) | ((unsigned)f2bf(b) << 16);
}
__device__ __forceinline__ float bf2f(unsigned short u) {
  return __uint_as_float(((unsigned)u) << 16);
}

// ---------------- Threefry-2x32 (bit-exact vs JAX, partitionable XOR mode) -----------
__device__ __forceinline__ void tf2x32(unsigned k0, unsigned k1,
                                       unsigned x0, unsigned x1,
                                       unsigned& o0, unsigned& o1) {
  unsigned ks2 = k0 ^ k1 ^ 0x1BD11BDAu;
  x0 += k0; x1 += k1;
#define TFR(r) { x0 += x1; x1 = (x1 << r) | (x1 >> (32 - r)); x1 ^= x0; }
  TFR(13) TFR(15) TFR(26) TFR(6)   x0 += k1;  x1 += ks2 + 1u;
  TFR(17) TFR(29) TFR(16) TFR(24)  x0 += ks2; x1 += k0 + 2u;
  TFR(13) TFR(15) TFR(26) TFR(6)   x0 += k0;  x1 += k1 + 3u;
  TFR(17) TFR(29) TFR(16) TFR(24)  x0 += k1;  x1 += ks2 + 4u;
  TFR(13) TFR(15) TFR(26) TFR(6)   x0 += ks2; x1 += k0 + 5u;
#undef TFR
  o0 = x0; o1 = x1;
}

__device__ __forceinline__ float bits_to_normal(unsigned bits) {
  float f = __uint_as_float((bits >> 9) | 0x3f800000u) - 1.0f;  // [0,1)
  const float lo = -0.99999994f;                                 // nextafter(-1,0)
  float x = fmaxf(lo, fmaf(f, 2.0f, lo));
  float w = -log1pf(-x * x);
  float p;
  if (w < 5.0f) {
    w = w - 2.5f;
    p = 2.81022636e-08f;
    p = fmaf(p, w, 3.43273939e-07f);
    p = fmaf(p, w, -3.5233877e-06f);
    p = fmaf(p, w, -4.39150654e-06f);
    p = fmaf(p, w, 0.00021858087f);
    p = fmaf(p, w, -0.00125372503f);
    p = fmaf(p, w, -0.00417768164f);
    p = fmaf(p, w, 0.246640727f);
    p = fmaf(p, w, 1.50140941f);
  } else {
    w = sqrtf(w) - 3.0f;
    p = -0.000200214257f;
    p = fmaf(p, w, 0.000100950558f);
    p = fmaf(p, w, 0.00134934322f);
    p = fmaf(p, w, -0.00367342844f);
    p = fmaf(p, w, 0.00573950773f);
    p = fmaf(p, w, -0.0076224613f);
    p = fmaf(p, w, 0.00943887047f);
    p = fmaf(p, w, 1.00167406f);
    p = fmaf(p, w, 2.83297682f);
  }
  return 1.41421356237f * (p * x);
}

// ---------------- shared-memory types ----------------
struct SmemGemm {
  unsigned short Xt[64 * XPITCH];
  float aColP[132], bColP[132];
  float bsum[128], bssq[128];
};
struct SmemVe {
  float cat[2][256], vres[2][128], lgs[2][KK], mrow[2][KK * DD], alsh[2][KK];
};
struct SmemH {
  float prerow[2][FF];
  float trow[2][128];
};
struct SmemOut {
  float nz[4][8][2], ins[4][8][2], alsh[4][KK];
};

struct Params {
  const float *data, *rtg, *rth, *I_HG, *v;
  const float *W1g, *b1g, *g1g, *be1g, *W2g, *b2g, *g2g, *be2g;
  const float *W1h, *b1h, *g1h, *be1h, *W2h, *b2h, *g2h, *be2h;
  const float *Wo1, *bo1, *Wa, *ba, *Wm, *bm;
  unsigned short *Ybf, *WtG;
  float *stats1, *stats2, *statsh1, *statsh2, *scaleg, *scaleh;
  float *hg, *hh, *y1h, *y2h, *va, *vmu, *vcore, *partials, *partial2;
  float *out;
};

// ================= phase functions ==============

__device__ __forceinline__ void prep_phase(const Params& p, int bid, int nblk, int tid) {
  for (int i = bid * 256 + tid; i < ROWS + HROWS; i += nblk * 256) {
    if (i < ROWS) {
      float4 r = ((const float4*)p.rtg)[i];
      p.scaleg[i] = (r.x + r.y + r.z + r.w) * 0.25f;
    } else {
      float4 r = ((const float4*)p.rth)[i - ROWS];
      p.scaleh[i - ROWS] = (r.x + r.y + r.z + r.w) * 0.25f;
    }
  }
  for (int i = bid * 256 + tid; i < 32768; i += nblk * 256) {
    int w = i >> 14, rem = i & 16383;
    int c = rem & 127, k = rem >> 7;
    const float* W = w ? p.W2g : p.W1g;
    p.WtG[w * 16384 + c * 128 + k] = f2bf(W[k * 128 + c]);
  }
}

// grid-strided pipelined bf16 MFMA GEMM; per-block partial stats (no global atomics).
template <int MODE>
__device__ __forceinline__ void edge_gemm_phase(
    const Params& p, SmemGemm& sg, int bid, int nblk, int tid,
    const unsigned short* WtG, const unsigned short* Yin, unsigned short* Yout,
    const float* bias, const float* gmm, const float* beta,
    const float* stats_in) {
  const int lane = tid & 63, wid = tid >> 6;
  const int l15 = lane & 15, lq = lane >> 4;
  const int cb = wid * 32;
  const int rsi = tid >> 2, q = tid & 3, k0 = q * 32;

  if (tid < 128) {
    sg.bsum[tid] = 0.f; sg.bssq[tid] = 0.f;
    if (MODE == 1) {
      float s = stats_in[tid], ss = stats_in[128 + tid];
      float mu = s * (1.f / ROWS);
      float var = fmaxf(ss * (1.f / ROWS) - mu * mu, 0.f);
      float rs = 1.f / sqrtf(var + EPSF);
      float a = rs * gmm[tid];
      int pi = tid + (tid >> 5);
      sg.aColP[pi] = a; sg.bColP[pi] = beta[tid] - mu * a;
    }
  }

  const unsigned short* WA = WtG + (cb + l15) * 128 + lq * 8;
  bf16x8 a0[4], a1[4];
#pragma unroll
  for (int kc = 0; kc < 4; ++kc) {
    a0[kc] = *(const bf16x8*)(WA + kc * 32);
    a1[kc] = *(const bf16x8*)(WA + 16 * 128 + kc * 32);
  }
  float4 bi0 = *(const float4*)&bias[cb + lq * 4];
  float4 bi1 = *(const float4*)&bias[cb + 16 + lq * 4];
  f32x4 bv0 = {bi0.x, bi0.y, bi0.z, bi0.w};
  f32x4 bv1 = {bi1.x, bi1.y, bi1.z, bi1.w};
  f32x4 s0 = {0.f,0.f,0.f,0.f}, ss0 = {0.f,0.f,0.f,0.f};
  f32x4 s1 = {0.f,0.f,0.f,0.f}, ss1 = {0.f,0.f,0.f,0.f};

  float4 ra[4], rb[4];
  uint4  rw[4];

  auto LOAD = [&](int tile) {
    if (MODE == 0) {
      int g = tile * 64 + rsi;
      int b = g / EE; int e = g - b * EE;
      int i = e / 99; int jj = e - i * 99; int j = jj + ((jj >= i) ? 1 : 0);
      int vsrc = (q < 2) ? ((b * NN + i) * FF + q * 32)
                         : ((b * NN + j) * FF + (q - 2) * 32);
#pragma unroll
      for (int i2 = 0; i2 < 4; ++i2) {
        ra[i2] = *(const float4*)&p.v[vsrc + i2 * 8];
        rb[i2] = *(const float4*)&p.v[vsrc + i2 * 8 + 4];
      }
    } else {
      const unsigned short* src = Yin + (size_t)(tile * 64 + rsi) * 128 + k0;
#pragma unroll
      for (int i2 = 0; i2 < 4; ++i2) rw[i2] = *(const uint4*)&src[i2 * 8];
    }
  };
  auto WRITE = [&]() {
    if (MODE == 0) {
#pragma unroll
      for (int i2 = 0; i2 < 4; ++i2) {
        uint4 pk;
        pk.x = pk2(ra[i2].x, ra[i2].y); pk.y = pk2(ra[i2].z, ra[i2].w);
        pk.z = pk2(rb[i2].x, rb[i2].y); pk.w = pk2(rb[i2].z, rb[i2].w);
        *(uint4*)&sg.Xt[rsi * XPITCH + k0 + i2 * 8] = pk;
      }
    } else {
#pragma unroll
      for (int i2 = 0; i2 < 4; ++i2) {
        unsigned rr[4] = {rw[i2].x, rw[i2].y, rw[i2].z, rw[i2].w};
        unsigned ow[4];
#pragma unroll
        for (int u = 0; u < 4; ++u) {
          int k = k0 + i2 * 8 + u * 2;
          int p1 = k + (k >> 5);
          float xl = __uint_as_float(rr[u] << 16);
          float xh = __uint_as_float(rr[u] & 0xffff0000u);
          xl = lrelu(fmaf(xl, sg.aColP[p1], sg.bColP[p1]));
          xh = lrelu(fmaf(xh, sg.aColP[p1 + 1], sg.bColP[p1 + 1]));
          ow[u] = pk2(xl, xh);
        }
        uint4 pk; pk.x = ow[0]; pk.y = ow[1]; pk.z = ow[2]; pk.w = ow[3];
        *(uint4*)&sg.Xt[rsi * XPITCH + k0 + i2 * 8] = pk;
      }
    }
  };

  if (MODE == 1) __syncthreads();   // aColP/bColP visible before first WRITE

  LOAD(bid);
  for (int t = bid; t < NTILE; t += nblk) {
    if (t != bid) __syncthreads();  // prior tile's MFMA reads of Xt complete
    WRITE();
    if (t + nblk < NTILE) LOAD(t + nblk);   // prefetch overlaps MFMA+epilogue
    __syncthreads();                // Xt ready

    f32x4 acc[2][4];
#pragma unroll
    for (int a = 0; a < 2; ++a)
#pragma unroll
      for (int b2 = 0; b2 < 4; ++b2) acc[a][b2] = (f32x4){0.f, 0.f, 0.f, 0.f};
    const unsigned short* Bb = &sg.Xt[l15 * XPITCH + lq * 8];
#pragma unroll
    for (int kc = 0; kc < 4; ++kc) {
      int ko = kc * 32;
#pragma unroll
      for (int rbi = 0; rbi < 4; ++rbi) {
        bf16x8 bfr = *(const bf16x8*)(Bb + rbi * 16 * XPITCH + ko);
        acc[0][rbi] = __builtin_amdgcn_mfma_f32_16x16x32_bf16(a0[kc], bfr, acc[0][rbi], 0, 0, 0);
        acc[1][rbi] = __builtin_amdgcn_mfma_f32_16x16x32_bf16(a1[kc], bfr, acc[1][rbi], 0, 0, 0);
      }
    }

    int r0 = t * 64;
#pragma unroll
    for (int rbi = 0; rbi < 4; ++rbi) {
      size_t r = (size_t)(r0 + rbi * 16 + l15);
      f32x4 y0 = acc[0][rbi] + bv0;
      f32x4 y1 = acc[1][rbi] + bv1;
      uint2 w0; w0.x = pk2(y0.x, y0.y); w0.y = pk2(y0.z, y0.w);
      uint2 w1; w1.x = pk2(y1.x, y1.y); w1.y = pk2(y1.z, y1.w);
      *(uint2*)&Yout[r * 128 + cb + lq * 4] = w0;
      *(uint2*)&Yout[r * 128 + cb + 16 + lq * 4] = w1;
      s0 += y0; ss0 += y0 * y0;
      s1 += y1; ss1 += y1 * y1;
    }
  }

#pragma unroll
  for (int u = 0; u < 4; ++u) {
    atomicAdd(&sg.bsum[cb + lq * 4 + u], s0[u]);
    atomicAdd(&sg.bssq[cb + lq * 4 + u], ss0[u]);
    atomicAdd(&sg.bsum[cb + 16 + lq * 4 + u], s1[u]);
    atomicAdd(&sg.bssq[cb + 16 + lq * 4 + u], ss1[u]);
  }
  __syncthreads();
  if (tid < 128) {
    p.partials[(size_t)bid * 256 + tid] = sg.bsum[tid];
    p.partials[(size_t)bid * 256 + 128 + tid] = sg.bssq[tid];
  }
}

__device__ __forceinline__ void redA_phase(const float* partials, float* partial2,
                                           int nblk, int bid, int tid) {
  if (bid < 32) {
    float s = 0.f;
    for (int r = bid; r < nblk; r += 32) s += partials[(size_t)r * 256 + tid];
    partial2[bid * 256 + tid] = s;
  }
}
__device__ __forceinline__ void redB_phase(const float* partial2, float* stats,
                                           int bid, int tid) {
  if (bid == 0) {
    float s = 0.f;
#pragma unroll
    for (int r = 0; r < 32; ++r) s += partial2[r * 256 + tid];
    stats[tid] = s;
  }
}

__device__ __forceinline__ void recv_phase(const Params& p, int bid, int nblk, int tid) {
  const int sub = tid >> 7, h = tid & 127;
  float s = p.stats2[h], ss = p.stats2[128 + h];
  float mu = s * (1.f / ROWS);
  float var = fmaxf(ss * (1.f / ROWS) - mu * mu, 0.f);
  float rs = 1.f / sqrtf(var + EPSF);
  float a = rs * p.g2g[h]; float bc = p.be2g[h] - mu * a;
  for (int bn = bid * 2 + sub; bn < BN_CNT; bn += 2 * nblk) {
    int b = bn / NN, n = bn - b * NN;
    float sv = (h >= 64) ? p.v[(b * NN + n) * FF + (h - 64)] : 0.f;
    float acc = 0.f;
#pragma unroll 4
    for (int i = 0; i < NN; ++i) {
      if (i == n) continue;
      int e = i * 99 + ((n < i) ? n : n - 1);
      int row = b * EE + e;
      float y = bf2f(p.Ybf[(size_t)row * 128 + h]);
      float msgv = lrelu(y * a + bc);
      float pre = (h < 64) ? p.v[(b * NN + i) * FF + h] : sv;
      float ag = lrelu(fmaf(msgv, p.scaleg[row], pre));
      acc += ag;
    }
    p.hg[bn * 128 + h] = acc * 0.5f;
  }
}

// HROWS/BN_CNT divisible by strides -> uniform trip counts; __syncthreads safe.
__device__ __forceinline__ void h1_phase(const Params& p, SmemH& sh, int bid, int nblk, int tid) {
  const int sub = tid >> 7, ht = tid & 127;
  for (int bm = bid * 2 + sub; bm < HROWS; bm += 2 * nblk) {
    int b = bm / MM, m = bm - b * MM;
    if (ht < FF) {
      float s = 0.f;
      for (int n = 0; n < NN; ++n)
        s = fmaf(p.I_HG[(b * NN + n) * MM + m], p.v[(b * NN + n) * FF + ht], s);
      sh.prerow[sub][ht] = s;
    }
    __syncthreads();
    float y = p.b1h[ht];
    for (int f = 0; f < FF; ++f) y = fmaf(sh.prerow[sub][f], p.W1h[f * 128 + ht], y);
    p.y1h[bm * 128 + ht] = y;
    __syncthreads();
  }
}

__device__ __forceinline__ void cs_phase(const float* X, float* stats, int bid, int tid) {
  if (bid < 32) {
    int c = bid * 4 + (tid >> 6), rt = tid & 63;
    float s = 0.f, ss = 0.f;
    for (int r = rt; r < HROWS; r += 64) {
      float x = X[(size_t)r * 128 + c];
      s += x; ss += x * x;
    }
    for (int off = 32; off; off >>= 1) {
      s += __shfl_down(s, off, 64);
      ss += __shfl_down(ss, off, 64);
    }
    if (rt == 0) { stats[c] = s; stats[128 + c] = ss; }
  }
}

__device__ __forceinline__ void h2_phase(const Params& p, SmemH& sh, int bid, int nblk, int tid) {
  const int sub = tid >> 7, ht = tid & 127;
  float s = p.statsh1[ht], ss = p.statsh1[128 + ht];
  float mu = s * (1.f / HROWS);
  float var = fmaxf(ss * (1.f / HROWS) - mu * mu, 0.f);
  float rs = 1.f / sqrtf(var + EPSF);
  float a = rs * p.g1h[ht]; float bc = p.be1h[ht] - mu * a;
  for (int bm = bid * 2 + sub; bm < HROWS; bm += 2 * nblk) {
    sh.trow[sub][ht] = lrelu(p.y1h[bm * 128 + ht] * a + bc);
    __syncthreads();
    float y = p.b2h[ht];
    for (int f = 0; f < 128; ++f) y = fmaf(sh.trow[sub][f], p.W2h[f * 128 + ht], y);
    p.y2h[bm * 128 + ht] = y;
    __syncthreads();
  }
}

__device__ __forceinline__ void h3_phase(const Params& p, int bid, int nblk, int tid) {
  const int sub = tid >> 7, h = tid & 127;
  float s = p.statsh2[h], ss = p.statsh2[128 + h];
  float mu = s * (1.f / HROWS);
  float var = fmaxf(ss * (1.f / HROWS) - mu * mu, 0.f);
  float rs = 1.f / sqrtf(var + EPSF);
  float a = rs * p.g2h[h]; float bc = p.be2h[h] - mu * a;
  for (int bn = bid * 2 + sub; bn < BN_CNT; bn += 2 * nblk) {
    int b = bn / NN, n = bn - b * NN;
    float acc = 0.f;
    for (int m = 0; m < MM; ++m) {
      float x = lrelu(p.y2h[(b * MM + m) * 128 + h] * a + bc);
      acc = fmaf(x * p.scaleh[b * MM + m], p.I_HG[(b * NN + n) * MM + m], acc);
    }
    p.hh[bn * 128 + h] = acc * 0.5f;
  }
}

__device__ __forceinline__ void ve_phase(const Params& p, SmemVe& sv, int bid, int nblk, int tid) {
  const int sub = tid >> 7, ht = tid & 127;
  for (int bn = bid * 2 + sub; bn < BN_CNT; bn += 2 * nblk) {
    sv.cat[sub][ht] = p.hg[bn * 128 + ht];
    sv.cat[sub][128 + ht] = p.hh[bn * 128 + ht];
    __syncthreads();
    float vv = p.bo1[ht];
    for (int k = 0; k < 256; ++k)
      vv = fmaf(sv.cat[sub][k], p.Wo1[k * 128 + ht], vv);
    sv.vres[sub][ht] = lrelu(vv);
    __syncthreads();
    if (ht < KK) {
      float s = p.ba[ht];
      for (int f = 0; f < 128; ++f) s = fmaf(sv.vres[sub][f], p.Wa[f * KK + ht], s);
      sv.lgs[sub][ht] = s;
    } else if (ht >= 64 && ht < 64 + KK * DD) {
      int c = ht - 64;
      float s = p.bm[c];
      for (int f = 0; f < 128; ++f) s = fmaf(sv.vres[sub][f], p.Wm[f * (KK * DD) + c], s);
      sv.mrow[sub][c] = s;
      p.vmu[bn * (KK * DD) + c] = s;
    }
    __syncthreads();
    if (ht < KK) {
      float mx = sv.lgs[sub][0];
      for (int k2 = 1; k2 < KK; ++k2) mx = fmaxf(mx, sv.lgs[sub][k2]);
      float se = 0.f;
      for (int k2 = 0; k2 < KK; ++k2) se += expf(sv.lgs[sub][k2] - mx);
      float al = expf(sv.lgs[sub][ht] - mx) / se;
      sv.alsh[sub][ht] = al;
      p.va[bn * KK + ht] = al;
    }
    __syncthreads();
    if (ht < DD) {
      float s = 0.f;
      for (int k2 = 0; k2 < KK; ++k2)
        s = fmaf(sv.alsh[sub][k2], sv.mrow[sub][k2 * DD + ht], s);
      p.vcore[bn * DD + ht] = s;
    }
    __syncthreads();
  }
}

__device__ __forceinline__ void out_phase(const Params& p, SmemOut& so, int bid, int nblk, int tid) {
  const int ut = tid >> 6, t = tid & 63;
  for (int bn = bid * 4 + ut; bn < BN_CNT; bn += 4 * nblk) {
    if (t < 16) {
      int s = t >> 1, d = t & 1;
      unsigned fk0, fk1;
      tf2x32(0u, 1234u, 0u, (unsigned)s, fk0, fk1);
      unsigned flat = (unsigned)(bn * 2 + d);
      unsigned o0, o1;
      tf2x32(fk0, fk1, 0u, flat, o0, o1);
      so.nz[ut][s][d] = bits_to_normal(o0 ^ o1);
    }
    if (t < KK) so.alsh[ut][t] = p.va[bn * KK + t];
    __syncthreads();
    if (t < 2) {
      int d = t;
      float ins0 = p.data[bn * 16 + d];
      float core = p.vcore[bn * 2 + d];
      float pp = ins0;
      for (int s = 0; s < 8; ++s) {
        so.ins[ut][s][d] = pp;
        pp = (pp + core) + so.nz[ut][s][d];
        p.out[(bn * 8 + s) * 2 + d] = pp;
      }
    }
    __syncthreads();
    for (int q = t; q < 160; q += 64) {
      int k = q % KK;
      p.out[25600 + bn * 160 + q] = so.alsh[ut][k];
    }
    for (int q = t; q < 320; q += 64) {
      int s = q / 40, kd = q - s * 40, d = kd & 1;
      p.out[281600 + bn * 320 + q] = p.vmu[bn * 40 + kd] + so.ins[ut][s][d];
    }
    for (int q = t; q < 320; q += 64) p.out[793600 + bn * 320 + q] = 1.0f;
    __syncthreads();
  }
}

// ================= kernels =================
__global__ __launch_bounds__(256) void k_prepW(Params p) {
  prep_phase(p, blockIdx.x, gridDim.x, threadIdx.x);
}
__global__ __launch_bounds__(256, 2) void k_gemm0W(Params p) {
  __shared__ __align__(16) SmemGemm sg;
  edge_gemm_phase<0>(p, sg, blockIdx.x, gridDim.x, threadIdx.x, p.WtG, nullptr,
                     p.Ybf, p.b1g, nullptr, nullptr, nullptr);
}
__global__ __launch_bounds__(256, 2) void k_gemm1W(Params p) {
  __shared__ __align__(16) SmemGemm sg;
  edge_gemm_phase<1>(p, sg, blockIdx.x, gridDim.x, threadIdx.x, p.WtG + 16384,
                     p.Ybf, p.Ybf, p.b2g, p.g1g, p.be1g, p.stats1);
}
__global__ __launch_bounds__(256) void k_redAW(const float* partials, float* partial2, int nblk) {
  redA_phase(partials, partial2, nblk, blockIdx.x, threadIdx.x);
}
__global__ __launch_bounds__(256) void k_redBW(const float* partial2, float* stats) {
  redB_phase(partial2, stats, blockIdx.x, threadIdx.x);
}
__global__ __launch_bounds__(256) void k_recvW(Params p) {
  recv_phase(p, blockIdx.x, gridDim.x, threadIdx.x);
}
__global__ __launch_bounds__(256) void k_h1W(Params p) {
  __shared__ SmemH sh;
  h1_phase(p, sh, blockIdx.x, gridDim.x, threadIdx.x);
}
__global__ __launch_bounds__(256) void k_csW(const float* X, float* stats) {
  cs_phase(X, stats, blockIdx.x, threadIdx.x);
}
__global__ __launch_bounds__(256) void k_h2W(Params p) {
  __shared__ SmemH sh;
  h2_phase(p, sh, blockIdx.x, gridDim.x, threadIdx.x);
}
__global__ __launch_bounds__(256) void k_h3W(Params p) {
  h3_phase(p, blockIdx.x, gridDim.x, threadIdx.x);
}
__global__ __launch_bounds__(256) void k_veW(Params p) {
  __shared__ SmemVe sv;
  ve_phase(p, sv, blockIdx.x, gridDim.x, threadIdx.x);
}
__global__ __launch_bounds__(256) void k_outW(Params p) {
  __shared__ SmemOut so;
  out_phase(p, so, blockIdx.x, gridDim.x, threadIdx.x);
}

extern "C" void kernel_launch(void* const* d_in, const int* in_sizes, int n_in,
                              void* d_out, int out_size, void* d_ws, size_t ws_size,
                              hipStream_t stream) {
  char* wsb = (char*)d_ws;

  Params p;
  p.data = (const float*)d_in[0];
  p.rtg  = (const float*)d_in[3];
  p.rth  = (const float*)d_in[4];
  p.I_HG = (const float*)d_in[5];
  p.v    = (const float*)d_in[6];
  p.W1g  = (const float*)d_in[7];
  p.b1g  = (const float*)d_in[8];
  p.g1g  = (const float*)d_in[9];
  p.be1g = (const float*)d_in[10];
  p.W2g  = (const float*)d_in[11];
  p.b2g  = (const float*)d_in[12];
  p.g2g  = (const float*)d_in[13];
  p.be2g = (const float*)d_in[14];
  p.W1h  = (const float*)d_in[15];
  p.b1h  = (const float*)d_in[16];
  p.g1h  = (const float*)d_in[17];
  p.be1h = (const float*)d_in[18];
  p.W2h  = (const float*)d_in[19];
  p.b2h  = (const float*)d_in[20];
  p.g2h  = (const float*)d_in[21];
  p.be2h = (const float*)d_in[22];
  p.Wo1  = (const float*)d_in[23];
  p.bo1  = (const float*)d_in[24];
  p.Wa   = (const float*)d_in[25];
  p.ba   = (const float*)d_in[26];
  p.Wm   = (const float*)d_in[27];
  p.bm   = (const float*)d_in[28];

  p.Ybf     = (unsigned short*)wsb;                                  // 40,550,400 B
  p.stats1  = (float*)(wsb + 40550400);
  p.stats2  = p.stats1 + 256;
  p.statsh1 = p.stats2 + 256;
  p.statsh2 = p.statsh1 + 256;
  p.scaleg  = (float*)(wsb + 40550400 + 4096);
  p.scaleh  = p.scaleg + ROWS;
  p.hg      = p.scaleh + HROWS;
  p.hh      = p.hg + BN_CNT * 128;
  p.y1h     = p.hh + BN_CNT * 128;
  p.y2h     = p.y1h + HROWS * 128;
  p.va      = p.y2h + HROWS * 128;
  p.vmu     = p.va + BN_CNT * KK;
  p.vcore   = p.vmu + BN_CNT * KK * DD;
  p.WtG     = (unsigned short*)(p.vcore + BN_CNT * DD);              // 2*16384 bf16
  p.partials = (float*)(p.WtG + 2 * 16384);                          // 512*256 f32
  p.partial2 = p.partials + (size_t)GEMMB * 256;                     // 32*256 f32
  p.out     = (float*)d_out;

  k_prepW<<<256, 256, 0, stream>>>(p);
  k_gemm0W<<<GEMMB, 256, 0, stream>>>(p);
  k_redAW<<<32, 256, 0, stream>>>(p.partials, p.partial2, GEMMB);
  k_redBW<<<1, 256, 0, stream>>>(p.partial2, p.stats1);
  k_gemm1W<<<GEMMB, 256, 0, stream>>>(p);
  k_redAW<<<32, 256, 0, stream>>>(p.partials, p.partial2, GEMMB);
  k_redBW<<<1, 256, 0, stream>>>(p.partial2, p.stats2);
  k_recvW<<<800, 256, 0, stream>>>(p);
  k_h1W<<<400, 256, 0, stream>>>(p);
  k_csW<<<32, 256, 0, stream>>>(p.y1h, p.statsh1);
  k_h2W<<<400, 256, 0, stream>>>(p);
  k_csW<<<32, 256, 0, stream>>>(p.y2h, p.statsh2);
  k_h3W<<<800, 256, 0, stream>>>(p);
  k_veW<<<800, 256, 0, stream>>>(p);
  k_outW<<<400, 256, 0, stream>>>(p);
}